// Round 9
// baseline (506.270 us; speedup 1.0000x reference)
//
#include <hip/hip_runtime.h>
#include <math.h>

#define N_T 8000
#define N_D 6000
#define N_E 320000
#define N_B 16384
#define NSTRIP 12

typedef __attribute__((ext_vector_type(8))) short s16x8;
typedef __attribute__((ext_vector_type(8))) __bf16 bf16x8;
typedef __attribute__((ext_vector_type(4))) float f32x4;

static __device__ __forceinline__ f32x4 mfma16(s16x8 a, s16x8 b, f32x4 c) {
  return __builtin_amdgcn_mfma_f32_16x16x32_bf16(
      __builtin_bit_cast(bf16x8, a), __builtin_bit_cast(bf16x8, b), c, 0, 0, 0);
}

static __device__ __forceinline__ unsigned short f2bf(float f) {
  unsigned u = __float_as_uint(f);
  u += 0x7FFF + ((u >> 16) & 1);
  return (unsigned short)(u >> 16);
}

static __device__ __forceinline__ float bf2f(unsigned short u) {
  return __uint_as_float(((unsigned)u) << 16);
}

__device__ __forceinline__ float wave_sum(float v) {
  v += __shfl_xor(v, 32, 64);
  v += __shfl_xor(v, 16, 64);
  v += __shfl_xor(v, 8, 64);
  v += __shfl_xor(v, 4, 64);
  v += __shfl_xor(v, 2, 64);
  v += __shfl_xor(v, 1, 64);
  return v;
}

// ---------------- CSR build (merged T+D) ----------------
__global__ void k_hist2(const int* __restrict__ src, const int* __restrict__ tgt,
                        int* __restrict__ cnt) {
  int i = blockIdx.x * 256 + threadIdx.x;
  if (i < N_E) atomicAdd(&cnt[src[i]], 1);
  else if (i < 2 * N_E) atomicAdd(&cnt[N_T + tgt[i - N_E]], 1);
}

__global__ void k_scan2(const int* __restrict__ cnt, int* __restrict__ rp_t,
    int* __restrict__ cur_t, int* __restrict__ rp_d, int* __restrict__ cur_d) {
  const int* c = blockIdx.x ? cnt + N_T : cnt;
  const int n = blockIdx.x ? N_D : N_T;
  int* rp = blockIdx.x ? rp_d : rp_t;
  int* cur = blockIdx.x ? cur_d : cur_t;
  __shared__ int buf[1024];
  __shared__ int carry_s;
  if (threadIdx.x == 0) carry_s = 0;
  __syncthreads();
  for (int base = 0; base < n; base += 1024) {
    int c0 = carry_s;
    int i = base + (int)threadIdx.x;
    int v = (i < n) ? c[i] : 0;
    buf[threadIdx.x] = v;
    __syncthreads();
    for (int off = 1; off < 1024; off <<= 1) {
      int t = (threadIdx.x >= (unsigned)off) ? buf[threadIdx.x - off] : 0;
      __syncthreads();
      buf[threadIdx.x] += t;
      __syncthreads();
    }
    int incl = buf[threadIdx.x];
    if (i < n) { int e = c0 + incl - v; rp[i] = e; cur[i] = e; }
    __syncthreads();
    if (threadIdx.x == 0) carry_s = c0 + buf[1023];
    __syncthreads();
  }
  if (threadIdx.x == 0) rp[n] = carry_s;
}

__global__ void k_scatter2(const int* __restrict__ src, const int* __restrict__ tgt,
    int* __restrict__ cur_t, int* __restrict__ cur_d,
    int* __restrict__ nbr_t, int* __restrict__ nbr_d) {
  int i = blockIdx.x * 256 + threadIdx.x;
  if (i < N_E) {
    int p = atomicAdd(&cur_t[src[i]], 1);
    nbr_t[p] = tgt[i];
  } else if (i < 2 * N_E) {
    i -= N_E;
    int p = atomicAdd(&cur_d[tgt[i]], 1);
    nbr_d[p] = src[i];
  }
}

// ---------------- fat precompute: pgemm (0..7) | wvec6 (8..13) | tobf16 (14..891) ----------------
__global__ __launch_bounds__(256) void k_pre(const float* __restrict__ th,
    const float* __restrict__ dh, float* __restrict__ P_t, float* __restrict__ P_d,
    const float* __restrict__ WsT, const float* __restrict__ aT,
    const float* __restrict__ WsD, const float* __restrict__ aD, float* __restrict__ wv,
    const float* __restrict__ c0, unsigned short* __restrict__ y0,
    const float* __restrict__ c1, unsigned short* __restrict__ y1,
    const float* __restrict__ c2, unsigned short* __restrict__ y2,
    const float* __restrict__ c3, unsigned short* __restrict__ y3) {
  int bx = blockIdx.x;
  if (bx < 8) {
    const float* A = bx < 4 ? th : dh;
    float* C = bx < 4 ? P_t : P_d;
    const int sub = bx & 3;
    const int row0 = (sub >> 1) * 64, col0 = (sub & 1) * 64;
    __shared__ float As[16][65];
    __shared__ float Bs[16][65];
    const int tid = threadIdx.x;
    const int tr = tid >> 4, tc = tid & 15;
    float acc[4][4] = {};
    for (int k0 = 0; k0 < 256; k0 += 16) {
      {
        int m = tid >> 2, kk = (tid & 3) * 4;
        float4 v = *(const float4*)(A + (size_t)(row0 + m) * 256 + k0 + kk);
        As[kk + 0][m] = v.x; As[kk + 1][m] = v.y; As[kk + 2][m] = v.z; As[kk + 3][m] = v.w;
      }
      {
        int nn = tid >> 2, kk = (tid & 3) * 4;
        float4 v = *(const float4*)(A + (size_t)(col0 + nn) * 256 + k0 + kk);
        Bs[kk + 0][nn] = v.x; Bs[kk + 1][nn] = v.y; Bs[kk + 2][nn] = v.z; Bs[kk + 3][nn] = v.w;
      }
      __syncthreads();
#pragma unroll
      for (int k = 0; k < 16; ++k) {
        float a[4], b[4];
#pragma unroll
        for (int i = 0; i < 4; ++i) a[i] = As[k][tr * 4 + i];
#pragma unroll
        for (int j = 0; j < 4; ++j) b[j] = Bs[k][tc * 4 + j];
#pragma unroll
        for (int i = 0; i < 4; ++i)
#pragma unroll
          for (int j = 0; j < 4; ++j)
            acc[i][j] = fmaf(a[i], b[j], acc[i][j]);
      }
      __syncthreads();
    }
#pragma unroll
    for (int i = 0; i < 4; ++i)
#pragma unroll
      for (int j = 0; j < 4; ++j)
        C[(size_t)(row0 + tr * 4 + i) * 128 + col0 + tc * 4 + j] = acc[i][j];
  } else if (bx < 14) {
    if (threadIdx.x >= 128) return;
    int b = bx - 8, k = threadIdx.x;
    const float* W = b < 3 ? WsT + b * 16384 : WsD + (b - 3) * 16384;
    const float* a = b < 3 ? aT + b * 256 : aD + (b - 3) * 256;
    float s = 0.f;
    for (int n = 0; n < 128; ++n) s = fmaf(W[n * 128 + k], a[n], s);
    wv[b * 128 + k] = s;
  } else {
    int i = (bx - 14) * 256 + threadIdx.x;
    const float* x; unsigned short* y;
    if (i < 12288) { x = c0; y = y0; }
    else if (i < 24576) { x = c1; y = y1; i -= 12288; }
    else if (i < 32768) { x = c2; y = y2; i -= 24576; }
    else if (i < 224768) { x = c3; y = y3; i -= 32768; }
    else return;
    float4 v = ((const float4*)x)[i];
    ushort4 o;
    o.x = f2bf(v.x); o.y = f2bf(v.y); o.z = f2bf(v.z); o.w = f2bf(v.w);
    ((ushort4*)y)[i] = o;
  }
}

// ---------------- bf16 MFMA GEMM body, N=128 fixed, 32-row tile ----------------
template<int K, int ACT, int BIAS, int SJMODE, int OUTF, int OUTB>
static __device__ __forceinline__ void mfma_body(
    const unsigned short* __restrict__ A, const unsigned short* __restrict__ B,
    const float* __restrict__ bias, const float* __restrict__ a2,
    float* __restrict__ Cf, unsigned short* __restrict__ Cb,
    float* __restrict__ sj_out, int M, int bx) {
  const int wave = threadIdx.x >> 6, lane = threadIdx.x & 63;
  const int row0 = bx * 32;
  const int col0 = wave * 32;
  const int l15 = lane & 15, kg = lane >> 4;
  constexpr int NS = K / 32;
  f32x4 acc[2][2] = {};
  s16x8 ab[2][2], bb[2][2];
  auto ld = [&](int buf, int k0) {
#pragma unroll
    for (int i = 0; i < 2; ++i) {
      int r = row0 + i * 16 + l15;
      ab[buf][i] = (r < M) ? *(const s16x8*)(A + (size_t)r * K + k0 + kg * 8) : (s16x8)0;
    }
#pragma unroll
    for (int j = 0; j < 2; ++j) {
      int c = col0 + j * 16 + l15;
      bb[buf][j] = *(const s16x8*)(B + (size_t)c * K + k0 + kg * 8);
    }
  };
  ld(0, 0);
#pragma unroll
  for (int s = 0; s < NS; ++s) {
    if (s + 1 < NS) ld((s + 1) & 1, (s + 1) * 32);
#pragma unroll
    for (int i = 0; i < 2; ++i)
#pragma unroll
      for (int j = 0; j < 2; ++j)
        acc[i][j] = mfma16(ab[s & 1][i], bb[s & 1][j], acc[i][j]);
  }
  __shared__ float sjl[4][32];
  float a2v[2];
  if (SJMODE) {
#pragma unroll
    for (int j = 0; j < 2; ++j) a2v[j] = a2[col0 + j * 16 + l15];
  }
#pragma unroll
  for (int i = 0; i < 2; ++i) {
    float part[4] = {0.f, 0.f, 0.f, 0.f};
#pragma unroll
    for (int j = 0; j < 2; ++j) {
      int gc = col0 + j * 16 + l15;
      float bv = BIAS ? bias[gc] : 0.f;
#pragma unroll
      for (int r = 0; r < 4; ++r) {
        int gr = row0 + i * 16 + kg * 4 + r;
        float v = acc[i][j][r] + bv;
        if (SJMODE == 1) part[r] += v * a2v[j];
        if (ACT == 1) v = v > 0.f ? v : __expf(v) - 1.f;
        if (ACT == 2) v = fmaxf(v, 0.f);
        if (SJMODE == 2) part[r] += v * a2v[j];
        if (gr < M) {
          if (OUTF) Cf[(size_t)gr * 128 + gc] = v;
          if (OUTB) Cb[(size_t)gr * 128 + gc] = f2bf(v);
        }
      }
    }
    if (SJMODE) {
#pragma unroll
      for (int r = 0; r < 4; ++r) {
        float p = part[r];
        p += __shfl_xor(p, 1, 64);
        p += __shfl_xor(p, 2, 64);
        p += __shfl_xor(p, 4, 64);
        p += __shfl_xor(p, 8, 64);
        if (l15 == 0) sjl[wave][i * 16 + kg * 4 + r] = p;
      }
    }
  }
  if (SJMODE) {
    __syncthreads();
    if (threadIdx.x < 32) {
      int gr = row0 + (int)threadIdx.x;
      if (gr < M)
        sj_out[gr] = sjl[0][threadIdx.x] + sjl[1][threadIdx.x] +
                     sjl[2][threadIdx.x] + sjl[3][threadIdx.x];
    }
  }
}

template<int K, int ACT, int BIAS, int SJMODE, int OUTF, int OUTB>
__global__ __launch_bounds__(256) void k_mfma(const unsigned short* __restrict__ A,
    const unsigned short* __restrict__ B, const float* __restrict__ bias,
    const float* __restrict__ a2, float* __restrict__ Cf, unsigned short* __restrict__ Cb,
    float* __restrict__ sj_out, int M) {
  mfma_body<K, ACT, BIAS, SJMODE, OUTF, OUTB>(A, B, bias, a2, Cf, Cb, sj_out, M, blockIdx.x);
}

template<int K, int ACT, int SJMODE, int OUTF, int OUTB>
__global__ __launch_bounds__(256) void k_mfma2(
    const unsigned short* __restrict__ A0, const unsigned short* __restrict__ B0,
    const float* __restrict__ a20, float* __restrict__ Cf0,
    unsigned short* __restrict__ Cb0, float* __restrict__ sj0, int M0, int G0,
    const unsigned short* __restrict__ A1, const unsigned short* __restrict__ B1,
    const float* __restrict__ a21, float* __restrict__ Cf1,
    unsigned short* __restrict__ Cb1, float* __restrict__ sj1, int M1) {
  int bx = blockIdx.x;
  if (bx < G0)
    mfma_body<K, ACT, 0, SJMODE, OUTF, OUTB>(A0, B0, nullptr, a20, Cf0, Cb0, sj0, M0, bx);
  else
    mfma_body<K, ACT, 0, SJMODE, OUTF, OUTB>(A1, B1, nullptr, a21, Cf1, Cb1, sj1, M1, bx - G0);
}

// ---------------- NCE v5: 32x64 per wave (low regs -> 4 waves/SIMD), no col guard ----------------
// z1 pre-scaled by 2; z2 zero-padded to tile multiple (pad cols add exp(0)=1 each,
// subtracted as a constant in k_contrast).
__global__ __launch_bounds__(256) void k_nce5(
    const unsigned short* __restrict__ z1t, const unsigned short* __restrict__ z2t,
    float* __restrict__ rs_tp,
    const unsigned short* __restrict__ z1d, const unsigned short* __restrict__ z2d,
    float* __restrict__ rs_dp) {
  const int wave = threadIdx.x >> 6, lane = threadIdx.x & 63;
  const int l15 = lane & 15, kg = lane >> 4;
  int by = blockIdx.y;
  const unsigned short *z1, *z2; float* rowsum; int M, N;
  if (by < 125) { z1 = z1t; z2 = z2t; rowsum = rs_tp; M = N_T; N = N_T; }
  else { by -= 125; z1 = z1d; z2 = z2d; rowsum = rs_dp; M = N_D; N = N_D; }
  const int row0 = by * 64 + (wave & 1) * 32;
  const int colw = (wave >> 1) * 64;
  const int CT = (N + 127) >> 7;
  const int ctps = (CT + NSTRIP - 1) / NSTRIP;
  const int ct0 = blockIdx.x * ctps;
  const int ct1 = min(CT, ct0 + ctps);
  const int nct = ct1 - ct0;
  if (nct <= 0) return;
  s16x8 a[4][2];
#pragma unroll
  for (int ks = 0; ks < 4; ++ks)
#pragma unroll
    for (int i = 0; i < 2; ++i) {
      int r = row0 + i * 16 + l15;
      a[ks][i] = (r < M) ? *(const s16x8*)(z1 + (size_t)r * 128 + ks * 32 + kg * 8) : (s16x8)0;
    }
  s16x8 b[2][4];
  auto ldb = [&](int buf, int ct, int ks) {
    const unsigned short* base = z2 + (size_t)(ct * 128 + colw) * 128 + ks * 32 + kg * 8;
#pragma unroll
    for (int j = 0; j < 4; ++j)
      b[buf][j] = *(const s16x8*)(base + (size_t)(j * 16 + l15) * 128);
  };
  float rs[2][4] = {};
  int cs = by % nct;          // stagger start tile per row-block (de-convoy L2)
  ldb(0, ct0 + cs, 0);
  for (int cc = 0; cc < nct; ++cc) {
    const int ct = ct0 + cs;
    const int csn = (cs + 1 == nct) ? 0 : cs + 1;
    f32x4 acc[2][4] = {};
#pragma unroll
    for (int ks = 0; ks < 4; ++ks) {
      if (ks < 3) ldb((ks + 1) & 1, ct, ks + 1);
      else if (cc + 1 < nct) ldb(0, ct0 + csn, 0);  // prefetch next tile under epilogue
#pragma unroll
      for (int i = 0; i < 2; ++i)
#pragma unroll
        for (int j = 0; j < 4; ++j)
          acc[i][j] = mfma16(a[ks][i], b[ks & 1][j], acc[i][j]);
    }
#pragma unroll
    for (int j = 0; j < 4; ++j)
#pragma unroll
      for (int i = 0; i < 2; ++i)
#pragma unroll
        for (int r = 0; r < 4; ++r)
          rs[i][r] += __expf(acc[i][j][r]);   // acc = 2*sim (z1 pre-scaled)
    cs = csn;
  }
#pragma unroll
  for (int i = 0; i < 2; ++i)
#pragma unroll
    for (int r = 0; r < 4; ++r) {
      float v = rs[i][r];
      v += __shfl_xor(v, 1, 64);
      v += __shfl_xor(v, 2, 64);
      v += __shfl_xor(v, 4, 64);
      v += __shfl_xor(v, 8, 64);
      if (l15 == 0) {
        int gr = row0 + i * 16 + kg * 4 + r;
        if (gr < M) atomicAdd(&rowsum[gr], v);
      }
    }
}

// ---------------- G partials: both sides, 128-way split-K each ----------------
__global__ __launch_bounds__(256) void k_syrk2m(const unsigned short* __restrict__ xbT,
    const unsigned short* __restrict__ xbD, float* __restrict__ partT,
    float* __restrict__ partD) {
  int b = blockIdx.x;
  const unsigned short* xb; float* part; int n;
  if (b < 128) { xb = xbT; part = partT + (size_t)b * 16384; n = N_T; }
  else { b -= 128; xb = xbD; part = partD + (size_t)b * 16384; n = N_D; }
  __shared__ float rows[4][128];
  int chunk = (n + 127) >> 7;
  int m0 = b * chunk, m1 = min(n, m0 + chunk);
  int tx = threadIdx.x & 15, ty = threadIdx.x >> 4;
  float acc[8][8] = {};
  for (int m = m0; m < m1; m += 4) {
    int nr = min(4, m1 - m);
    if ((int)threadIdx.x < nr * 64) {
      ushort2 u = ((const ushort2*)(xb + (size_t)m * 128))[threadIdx.x];
      rows[threadIdx.x >> 6][(threadIdx.x & 63) * 2] = bf2f(u.x);
      rows[threadIdx.x >> 6][(threadIdx.x & 63) * 2 + 1] = bf2f(u.y);
    }
    __syncthreads();
    for (int r = 0; r < nr; ++r) {
      float a[8], bv[8];
#pragma unroll
      for (int i = 0; i < 8; ++i) a[i] = rows[r][i * 16 + ty];
#pragma unroll
      for (int j = 0; j < 8; ++j) bv[j] = rows[r][j * 16 + tx];
#pragma unroll
      for (int i = 0; i < 8; ++i)
#pragma unroll
        for (int j = 0; j < 8; ++j)
          acc[i][j] = fmaf(a[i], bv[j], acc[i][j]);
    }
    __syncthreads();
  }
#pragma unroll
  for (int i = 0; i < 8; ++i)
#pragma unroll
    for (int j = 0; j < 8; ++j)
      part[(i * 16 + ty) * 128 + j * 16 + tx] = acc[i][j];
}

__global__ void k_redm(const float* __restrict__ partT, const float* __restrict__ partD,
                       float* __restrict__ GmT, float* __restrict__ GmD) {
  int b = blockIdx.x;
  const float* part = b < 64 ? partT : partD;
  float* G = b < 64 ? GmT : GmD;
  int i = (b & 63) * 256 + threadIdx.x;
  float s = 0.f;
  for (int c = 0; c < 128; ++c) s += part[(size_t)c * 16384 + i];
  G[i] = s;
}

// ---------------- Wt = G @ P -> bf16, both sides (8 blocks) ----------------
__global__ __launch_bounds__(256) void k_wtm(const float* __restrict__ GmT,
    const float* __restrict__ P_t, unsigned short* __restrict__ wb_t,
    const float* __restrict__ GmD, const float* __restrict__ P_d,
    unsigned short* __restrict__ wb_d) {
  const float* G = blockIdx.x < 4 ? GmT : GmD;
  const float* P = blockIdx.x < 4 ? P_t : P_d;
  unsigned short* wb = blockIdx.x < 4 ? wb_t : wb_d;
  const int sub = blockIdx.x & 3;
  const int bi = sub >> 1, bj = sub & 1;
  __shared__ float Gs[64][129];
  __shared__ float Ps[128][65];
  for (int t = threadIdx.x; t < 8192; t += 256) {
    int il = t >> 7, k = t & 127;
    Gs[il][k] = G[(bi * 64 + il) * 128 + k];
    int pk = t >> 6, pj = t & 63;
    Ps[pk][pj] = P[pk * 128 + bj * 64 + pj];
  }
  __syncthreads();
  const int tx = threadIdx.x & 15, ty = threadIdx.x >> 4;
  float acc[4][4] = {};
  for (int k = 0; k < 128; ++k) {
    float a[4], b[4];
#pragma unroll
    for (int i = 0; i < 4; ++i) a[i] = Gs[ty * 4 + i][k];
#pragma unroll
    for (int j = 0; j < 4; ++j) b[j] = Ps[k][tx * 4 + j];
#pragma unroll
    for (int i = 0; i < 4; ++i)
#pragma unroll
      for (int j = 0; j < 4; ++j)
        acc[i][j] = fmaf(a[i], b[j], acc[i][j]);
  }
#pragma unroll
  for (int i = 0; i < 4; ++i)
#pragma unroll
    for (int j = 0; j < 4; ++j)
      wb[(bi * 64 + ty * 4 + i) * 128 + bj * 64 + tx * 4 + j] = f2bf(acc[i][j]);
}

__global__ void k_rowdot2(const float* __restrict__ trna, const float* __restrict__ dis,
    const float* __restrict__ wv, float* __restrict__ si_ta, float* __restrict__ si_da) {
  int r = blockIdx.x * 4 + (threadIdx.x >> 6);
  int lane = threadIdx.x & 63;
  const float* h; const float* a; float* o; int row;
  if (r < N_T) { h = trna; a = wv; o = si_ta; row = r; }
  else {
    row = r - N_T;
    if (row >= N_D) return;
    h = dis; a = wv + 3 * 128; o = si_da;
  }
  float2 v = *(const float2*)(h + (size_t)row * 128 + lane * 2);
  float2 av = *(const float2*)(a + lane * 2);
  float s = v.x * av.x + v.y * av.y;
  s = wave_sum(s);
  if (lane == 0) o[row] = s;
}

// ---------------- aggregation: 1 row/wave, 2 cols/lane, 16-edge ILP ----------------
template<int OUTF, int OUTB, int EMIT_SI>
static __device__ __forceinline__ void agg_body(const int* __restrict__ rp,
    const int* __restrict__ nbr, const float* __restrict__ si,
    const float* __restrict__ sj, const unsigned short* __restrict__ hjb,
    float* __restrict__ outF, unsigned short* __restrict__ outB,
    const float* __restrict__ wv, float* __restrict__ si_out, int n, int bx) {
  int r = bx * 4 + ((int)threadIdx.x >> 6);
  int lane = threadIdx.x & 63;
  if (r >= n) return;
  int p0 = rp[r], p1 = rp[r + 1];
  float sir = si[r];
  int c2 = lane * 2;
  auto wgt = [&](float sv) {
    float v = sir + sv;
    v = v >= 0.f ? v : 0.2f * v;
    v = fminf(30.f, fmaxf(-30.f, v));
    return __expf(v);
  };
  float ax = 0.f, ay = 0.f, den = 0.f;
  int p = p0;
  for (; p + 16 <= p1; p += 16) {
    int t[16]; float sv[16]; ushort2 h[16];
#pragma unroll
    for (int k = 0; k < 16; ++k) t[k] = nbr[p + k];
#pragma unroll
    for (int k = 0; k < 16; ++k) sv[k] = sj[t[k]];
#pragma unroll
    for (int k = 0; k < 16; ++k) h[k] = *(const ushort2*)(hjb + (size_t)t[k] * 128 + c2);
#pragma unroll
    for (int k = 0; k < 16; ++k) {
      float w = wgt(sv[k]);
      den += w;
      ax += w * bf2f(h[k].x);
      ay += w * bf2f(h[k].y);
    }
  }
  for (; p + 4 <= p1; p += 4) {
    int t[4]; float sv[4]; ushort2 h[4];
#pragma unroll
    for (int k = 0; k < 4; ++k) t[k] = nbr[p + k];
#pragma unroll
    for (int k = 0; k < 4; ++k) sv[k] = sj[t[k]];
#pragma unroll
    for (int k = 0; k < 4; ++k) h[k] = *(const ushort2*)(hjb + (size_t)t[k] * 128 + c2);
#pragma unroll
    for (int k = 0; k < 4; ++k) {
      float w = wgt(sv[k]);
      den += w;
      ax += w * bf2f(h[k].x);
      ay += w * bf2f(h[k].y);
    }
  }
  for (; p < p1; ++p) {
    int t = nbr[p];
    float w = wgt(sj[t]);
    ushort2 h = *(const ushort2*)(hjb + (size_t)t * 128 + c2);
    den += w;
    ax += w * bf2f(h.x);
    ay += w * bf2f(h.y);
  }
  float inv = 1.0f / (den + 1e-8f);
  float vx = ax * inv, vy = ay * inv;
  vx = vx > 0.f ? vx : __expf(vx) - 1.f;
  vy = vy > 0.f ? vy : __expf(vy) - 1.f;
  if (OUTF) {
    float2 of; of.x = vx; of.y = vy;
    *(float2*)(outF + (size_t)r * 128 + c2) = of;
  }
  if (OUTB) {
    ushort2 ob; ob.x = f2bf(vx); ob.y = f2bf(vy);
    *(ushort2*)(outB + (size_t)r * 128 + c2) = ob;
  }
  if (EMIT_SI) {
    float2 w2v = *(const float2*)(wv + c2);
    float d = vx * w2v.x + vy * w2v.y;
    d = wave_sum(d);
    if (lane == 0) si_out[r] = d;
  }
}

template<int OUTF, int OUTB, int EMIT_SI>
__global__ __launch_bounds__(256) void k_agg(const int* __restrict__ rp,
    const int* __restrict__ nbr, const float* __restrict__ si,
    const float* __restrict__ sj, const unsigned short* __restrict__ hjb,
    float* __restrict__ outF, unsigned short* __restrict__ outB,
    const float* __restrict__ wv, float* __restrict__ si_out, int n) {
  agg_body<OUTF, OUTB, EMIT_SI>(rp, nbr, si, sj, hjb, outF, outB, wv, si_out, n, blockIdx.x);
}

template<int OUTF, int OUTB, int EMIT_SI>
__global__ __launch_bounds__(256) void k_agg2(
    const int* __restrict__ rp0, const int* __restrict__ nbr0, const float* __restrict__ si0,
    const float* __restrict__ sj0, const unsigned short* __restrict__ hjb0,
    float* __restrict__ outF0, unsigned short* __restrict__ outB0,
    const float* __restrict__ wv0, float* __restrict__ sio0, int n0, int G0,
    const int* __restrict__ rp1, const int* __restrict__ nbr1, const float* __restrict__ si1,
    const float* __restrict__ sj1, const unsigned short* __restrict__ hjb1,
    float* __restrict__ outF1, unsigned short* __restrict__ outB1,
    const float* __restrict__ wv1, float* __restrict__ sio1, int n1) {
  int bx = blockIdx.x;
  if (bx < G0)
    agg_body<OUTF, OUTB, EMIT_SI>(rp0, nbr0, si0, sj0, hjb0, outF0, outB0, wv0, sio0, n0, bx);
  else
    agg_body<OUTF, OUTB, EMIT_SI>(rp1, nbr1, si1, sj1, hjb1, outF1, outB1, wv1, sio1, n1, bx - G0);
}

// ---------------- normalize both z's per row + diag dot + rs zero + pad zero ----------------
// z1 outputs pre-scaled by 2 (1/TEMP) for the NCE kernel.
__global__ void k_norm2(const float* __restrict__ sgt, const float* __restrict__ hgt3,
    const float* __restrict__ sgd, const float* __restrict__ hgd3,
    unsigned short* __restrict__ z1t, unsigned short* __restrict__ z2t,
    unsigned short* __restrict__ z1d, unsigned short* __restrict__ z2d,
    float* __restrict__ rs_t, float* __restrict__ dg_t,
    float* __restrict__ rs_d, float* __restrict__ dg_d) {
  int ridx = blockIdx.x * 4 + (threadIdx.x >> 6);
  int lane = threadIdx.x & 63;
  const float *x1, *x2; unsigned short *o1, *o2; float *rs, *dg; int row;
  if (ridx < 8000) { x1 = sgt; x2 = hgt3; o1 = z1t; o2 = z2t; rs = rs_t; dg = dg_t; row = ridx; }
  else if (ridx < 14000) {
    row = ridx - 8000;
    x1 = sgd; x2 = hgd3; o1 = z1d; o2 = z2d; rs = rs_d; dg = dg_d;
  } else if (ridx < 14064) {   // zero z2t pad rows 8000..8063
    row = 8000 + (ridx - 14000);
    ushort2 z; z.x = 0; z.y = 0;
    *(ushort2*)(z2t + (size_t)row * 128 + lane * 2) = z;
    return;
  } else if (ridx < 14080) {   // zero z2d pad rows 6000..6015
    row = 6000 + (ridx - 14064);
    ushort2 z; z.x = 0; z.y = 0;
    *(ushort2*)(z2d + (size_t)row * 128 + lane * 2) = z;
    return;
  } else return;
  float2 v1 = *(const float2*)(x1 + (size_t)row * 128 + lane * 2);
  float2 v2 = *(const float2*)(x2 + (size_t)row * 128 + lane * 2);
  float ss1 = wave_sum(v1.x * v1.x + v1.y * v1.y);
  float ss2 = wave_sum(v2.x * v2.x + v2.y * v2.y);
  float i1 = 1.0f / (sqrtf(ss1) + 1e-12f);
  float i2 = 1.0f / (sqrtf(ss2) + 1e-12f);
  float n1x = v1.x * i1, n1y = v1.y * i1;
  float n2x = v2.x * i2, n2y = v2.y * i2;
  ushort2 w1; w1.x = f2bf(n1x + n1x); w1.y = f2bf(n1y + n1y);   // x2 fold
  ushort2 w2; w2.x = f2bf(n2x); w2.y = f2bf(n2y);
  *(ushort2*)(o1 + (size_t)row * 128 + lane * 2) = w1;
  *(ushort2*)(o2 + (size_t)row * 128 + lane * 2) = w2;
  float d = wave_sum(n1x * n2x + n1y * n2y);
  if (lane == 0) { dg[row] = 2.0f * d; rs[row] = 0.f; }
}

__global__ void k_gather(const float* __restrict__ sgt, const float* __restrict__ hgt,
    const float* __restrict__ sgd, const float* __restrict__ hgd,
    const int* __restrict__ tids, const int* __restrict__ dids,
    const float* __restrict__ gateW, unsigned short* __restrict__ mlp_in_b,
    float* __restrict__ gmf, float* __restrict__ gate_lin, int nB) {
  int b = blockIdx.x * 4 + (threadIdx.x >> 6);
  int lane = threadIdx.x & 63;
  if (b >= nB) return;
  int ti = tids[b], di = dids[b];
  float2 a1 = *(const float2*)(sgt + (size_t)ti * 128 + lane * 2);
  float2 a2 = *(const float2*)(hgt + (size_t)ti * 128 + lane * 2);
  float2 c1 = *(const float2*)(sgd + (size_t)di * 128 + lane * 2);
  float2 c2 = *(const float2*)(hgd + (size_t)di * 128 + lane * 2);
  float2 st; st.x = a1.x + a2.x; st.y = a1.y + a2.y;
  float2 sd; sd.x = c1.x + c2.x; sd.y = c1.y + c2.y;
  ushort2 o1; o1.x = f2bf(st.x); o1.y = f2bf(st.y);
  ushort2 o2; o2.x = f2bf(sd.x); o2.y = f2bf(sd.y);
  *(ushort2*)(mlp_in_b + (size_t)b * 256 + lane * 2) = o1;
  *(ushort2*)(mlp_in_b + (size_t)b * 256 + 128 + lane * 2) = o2;
  float2 gv; gv.x = st.x * sd.x; gv.y = st.y * sd.y;
  float2 gw = *(const float2*)(gateW + lane * 2);
  float s1 = gv.x + gv.y;
  float s2 = gv.x * gw.x + gv.y * gw.y;
  s1 = wave_sum(s1);
  s2 = wave_sum(s2);
  if (lane == 0) { gmf[b] = s1; gate_lin[b] = s2; }
}

__global__ void k_final(const float* __restrict__ h1, const float* __restrict__ W2,
    const float* __restrict__ b2, const float* __restrict__ gate_lin,
    const float* __restrict__ gate_b, const float* __restrict__ gmf,
    float* __restrict__ fusion, float* __restrict__ mlp_pred, int nB) {
  int b = blockIdx.x * 4 + (threadIdx.x >> 6);
  int lane = threadIdx.x & 63;
  if (b >= nB) return;
  float2 hv = *(const float2*)(h1 + (size_t)b * 128 + lane * 2);
  float2 wv = *(const float2*)(W2 + lane * 2);
  float s = hv.x * wv.x + hv.y * wv.y;
  s = wave_sum(s);
  if (lane == 0) {
    float mp = s + b2[0];
    float g = 1.0f / (1.0f + __expf(-(gate_lin[b] + gate_b[0])));
    mlp_pred[b] = mp;
    fusion[b] = g * gmf[b] + (1.0f - g) * mp;
  }
}

// pad-corrected: rowsum includes +PAD from zero pad columns (exp(0)=1 each)
__global__ void k_contrast(const float* __restrict__ rs_t, const float* __restrict__ dg_t,
    const float* __restrict__ rs_d, const float* __restrict__ dg_d, float* __restrict__ out) {
  __shared__ float red[256];
  float st = 0.f, sd = 0.f;
  for (int i = threadIdx.x; i < N_T; i += 256) st += __logf(rs_t[i] - 64.0f) - dg_t[i];
  for (int i = threadIdx.x; i < N_D; i += 256) sd += __logf(rs_d[i] - 16.0f) - dg_d[i];
  red[threadIdx.x] = st * (1.0f / N_T) + sd * (1.0f / N_D);
  __syncthreads();
  for (int off = 128; off; off >>= 1) {
    if (threadIdx.x < (unsigned)off) red[threadIdx.x] += red[threadIdx.x + off];
    __syncthreads();
  }
  if (threadIdx.x == 0) out[0] = red[0];
}

// ---------------- host orchestration ----------------
extern "C" void kernel_launch(void* const* d_in, const int* in_sizes, int n_in,
                              void* d_out, int out_size, void* d_ws, size_t ws_size,
                              hipStream_t stream) {
  const float* trna   = (const float*)d_in[0];
  const float* dis    = (const float*)d_in[1];
  const float* thyper = (const float*)d_in[2];
  const float* dhyper = (const float*)d_in[3];
  const float* WsrcT  = (const float*)d_in[4];
  const float* WtgtT  = (const float*)d_in[5];
  const float* aT     = (const float*)d_in[6];
  const float* WsrcD  = (const float*)d_in[7];
  const float* WtgtD  = (const float*)d_in[8];
  const float* aD     = (const float*)d_in[9];
  const float* W1     = (const float*)d_in[10];
  const float* b1     = (const float*)d_in[11];
  const float* W2     = (const float*)d_in[12];
  const float* b2     = (const float*)d_in[13];
  const float* gW     = (const float*)d_in[14];
  const float* gb     = (const float*)d_in[15];
  const int* src_id   = (const int*)d_in[16];
  const int* tgt_id   = (const int*)d_in[17];
  const int* tids     = (const int*)d_in[18];
  const int* dids     = (const int*)d_in[19];
  float* out = (float*)d_out;

  float* out_fusion = out;
  float* out_sgt    = out + 16384;
  float* out_sgd    = out + 16384 + 1024000;
  float* out_gmf    = out + 1808384;
  float* out_mlp    = out + 1824768;
  float* out_con    = out + 1841152;

  char* wsb = (char*)d_ws;
  size_t off = 0;
  auto alloc = [&](size_t bytes) -> void* {
    void* p = wsb + off;
    off += (bytes + 255) & ~(size_t)255;
    return p;
  };
  float* hg_t3  = (float*)alloc((size_t)N_T * 128 * 4);
  float* hg_d3  = (float*)alloc((size_t)N_D * 128 * 4);
  unsigned short* sgt_b  = (unsigned short*)alloc((size_t)N_T * 128 * 2);
  unsigned short* sgd_b  = (unsigned short*)alloc((size_t)N_D * 128 * 2);
  unsigned short* hgt_b  = (unsigned short*)alloc((size_t)N_T * 128 * 2);
  unsigned short* hgd_b  = (unsigned short*)alloc((size_t)N_D * 128 * 2);
  unsigned short* hgt2_b = (unsigned short*)alloc((size_t)N_T * 128 * 2);
  unsigned short* hgd2_b = (unsigned short*)alloc((size_t)N_D * 128 * 2);
  unsigned short* disb   = (unsigned short*)alloc((size_t)N_D * 128 * 2);
  unsigned short* hjbT   = (unsigned short*)alloc((size_t)N_T * 128 * 2);
  unsigned short* hjbD   = (unsigned short*)alloc((size_t)N_T * 128 * 2);
  unsigned short* zb1t = (unsigned short*)alloc((size_t)N_T * 128 * 2);
  unsigned short* zb2t = (unsigned short*)alloc((size_t)(N_T + 128) * 128 * 2);  // padded
  unsigned short* zb1d = (unsigned short*)alloc((size_t)N_D * 128 * 2);
  unsigned short* zb2d = (unsigned short*)alloc((size_t)(N_D + 128) * 128 * 2);  // padded
  unsigned short* wb_t = (unsigned short*)alloc(16384 * 2);
  unsigned short* wb_d = (unsigned short*)alloc(16384 * 2);
  unsigned short* wbT  = (unsigned short*)alloc(3 * 16384 * 2);
  unsigned short* wbD  = (unsigned short*)alloc(3 * 16384 * 2);
  unsigned short* W1b  = (unsigned short*)alloc(32768 * 2);
  unsigned short* mlp_in_b = (unsigned short*)alloc((size_t)N_B * 256 * 2);  // 8 MB
  float* h1buf  = (float*)alloc((size_t)N_B * 128 * 4);                      // 8 MB
  float* partT  = (float*)mlp_in_b;   // aliased, disjoint in time
  float* partD  = partT + (size_t)128 * 16384;
  float* Gm_t   = (float*)alloc(16384 * 4);
  float* Gm_d   = (float*)alloc(16384 * 4);
  float* P_t    = (float*)alloc(16384 * 4);
  float* P_d    = (float*)alloc(16384 * 4);
  float* wvecs  = (float*)alloc(6 * 128 * 4);
  float* si_ta  = (float*)alloc(N_T * 4);
  float* si_tb  = (float*)alloc(N_T * 4);
  float* si_da  = (float*)alloc(N_D * 4);
  float* si_db  = (float*)alloc(N_D * 4);
  float* s_jT   = (float*)alloc(N_T * 4);
  float* s_jD   = (float*)alloc(N_T * 4);
  int* cnt      = (int*)alloc((N_T + N_D) * 4);
  int* rp_t     = (int*)alloc((N_T + 1) * 4);
  int* cur_t    = (int*)alloc(N_T * 4);
  int* rp_d     = (int*)alloc((N_D + 1) * 4);
  int* cur_d    = (int*)alloc(N_D * 4);
  int* nbrc_t   = (int*)alloc((size_t)N_E * 4);
  int* nbrc_d   = (int*)alloc((size_t)N_E * 4);
  float* rs_t   = (float*)alloc(N_T * 4);
  float* dg_t   = (float*)alloc(N_T * 4);
  float* rs_d   = (float*)alloc(N_D * 4);
  float* dg_d   = (float*)alloc(N_D * 4);
  float* g_lin  = (float*)alloc(N_B * 4);
  (void)ws_size; (void)in_sizes; (void)n_in; (void)out_size;

  const int gT32 = (N_T + 31) / 32;   // 250
  const int gD32 = (N_D + 31) / 32;   // 188
  const int aT4 = (N_T + 3) / 4, aD4 = (N_D + 3) / 4;

  // ---- CSR ----
  hipMemsetAsync(cnt, 0, (N_T + N_D) * 4, stream);
  k_hist2<<<(2 * N_E + 255) / 256, 256, 0, stream>>>(src_id, tgt_id, cnt);
  k_scan2<<<2, 1024, 0, stream>>>(cnt, rp_t, cur_t, rp_d, cur_d);
  k_scatter2<<<(2 * N_E + 255) / 256, 256, 0, stream>>>(src_id, tgt_id, cur_t, cur_d,
      nbrc_t, nbrc_d);

  // ---- precomputes (fat kernel) + rowdot ----
  k_pre<<<892, 256, 0, stream>>>(thyper, dhyper, P_t, P_d,
      WsrcT, aT, WsrcD, aD, wvecs,
      WtgtT, wbT, WtgtD, wbD, W1, W1b, dis, disb);
  k_rowdot2<<<(N_T + N_D + 3) / 4, 256, 0, stream>>>(trna, dis, wvecs, si_ta, si_da);

  // ---- GAT layer 1 (serial T -> D) ----
  k_mfma<128, 0, 0, 1, 0, 1><<<gD32, 256, 0, stream>>>(
      disb, wbT, nullptr, aT + 128, nullptr, hjbT, s_jT, N_D);
  k_agg<0, 1, 0><<<aT4, 256, 0, stream>>>(rp_t, nbrc_t, si_ta, s_jT, hjbT,
      nullptr, sgt_b, nullptr, nullptr, N_T);
  k_mfma<128, 0, 0, 1, 0, 1><<<gT32, 256, 0, stream>>>(
      sgt_b, wbD, nullptr, aD + 128, nullptr, hjbD, s_jD, N_T);
  k_agg<0, 1, 0><<<aD4, 256, 0, stream>>>(rp_d, nbrc_d, si_da, s_jD, hjbD,
      nullptr, sgd_b, nullptr, nullptr, N_D);

  // ---- hypergraph pass 1 (merged T+D) ----
  k_syrk2m<<<256, 256, 0, stream>>>(sgt_b, sgd_b, partT, partD);
  k_redm<<<128, 256, 0, stream>>>(partT, partD, Gm_t, Gm_d);
  k_wtm<<<8, 256, 0, stream>>>(Gm_t, P_t, wb_t, Gm_d, P_d, wb_d);
  k_mfma2<128, 1, 0, 0, 1><<<gT32 + gD32, 256, 0, stream>>>(
      sgt_b, wb_t, nullptr, nullptr, hgt_b, nullptr, N_T, gT32,
      sgd_b, wb_d, nullptr, nullptr, hgd_b, nullptr, N_D);

  // ---- hypergraph pass 2 (merged; emits si for GAT2) ----
  k_syrk2m<<<256, 256, 0, stream>>>(hgt_b, hgd_b, partT, partD);
  k_redm<<<128, 256, 0, stream>>>(partT, partD, Gm_t, Gm_d);
  k_wtm<<<8, 256, 0, stream>>>(Gm_t, P_t, wb_t, Gm_d, P_d, wb_d);
  k_mfma2<128, 1, 2, 0, 1><<<gT32 + gD32, 256, 0, stream>>>(
      hgt_b, wb_t, wvecs + 128, nullptr, hgt2_b, si_tb, N_T, gT32,
      hgd_b, wb_d, wvecs + 4 * 128, nullptr, hgd2_b, si_db, N_D);

  // ---- GAT layer 2 (merged T+D) ----
  k_mfma2<128, 0, 1, 0, 1><<<gD32 + gT32, 256, 0, stream>>>(
      hgd2_b, wbT + 16384, aT + 256 + 128, nullptr, hjbT, s_jT, N_D, gD32,
      hgt2_b, wbD + 16384, aD + 256 + 128, nullptr, hjbD, s_jD, N_T);
  k_agg2<0, 1, 1><<<aT4 + aD4, 256, 0, stream>>>(
      rp_t, nbrc_t, si_tb, s_jT, hjbT, nullptr, sgt_b, wvecs + 2 * 128, si_ta, N_T, aT4,
      rp_d, nbrc_d, si_db, s_jD, hjbD, nullptr, sgd_b, wvecs + 5 * 128, si_da, N_D);

  // ---- GAT layer 3 (serial T -> D) ----
  k_mfma<128, 0, 0, 1, 0, 1><<<gD32, 256, 0, stream>>>(
      sgd_b, wbT + 32768, nullptr, aT + 512 + 128, nullptr, hjbT, s_jT, N_D);
  k_agg<1, 1, 0><<<aT4, 256, 0, stream>>>(rp_t, nbrc_t, si_ta, s_jT, hjbT,
      out_sgt, sgt_b, nullptr, nullptr, N_T);
  k_mfma<128, 0, 0, 1, 0, 1><<<gT32, 256, 0, stream>>>(
      sgt_b, wbD + 32768, nullptr, aD + 512 + 128, nullptr, hjbD, s_jD, N_T);
  k_agg<1, 0, 0><<<aD4, 256, 0, stream>>>(rp_d, nbrc_d, si_da, s_jD, hjbD,
      out_sgd, nullptr, nullptr, nullptr, N_D);

  // ---- hypergraph pass 3 (merged) ----
  k_syrk2m<<<256, 256, 0, stream>>>(hgt2_b, hgd2_b, partT, partD);
  k_redm<<<128, 256, 0, stream>>>(partT, partD, Gm_t, Gm_d);
  k_wtm<<<8, 256, 0, stream>>>(Gm_t, P_t, wb_t, Gm_d, P_d, wb_d);
  k_mfma2<128, 1, 0, 1, 0><<<gT32 + gD32, 256, 0, stream>>>(
      hgt2_b, wb_t, nullptr, hg_t3, nullptr, nullptr, N_T, gT32,
      hgd2_b, wb_d, nullptr, hg_d3, nullptr, nullptr, N_D);

  // ---- InfoNCE ----
  k_norm2<<<3520, 256, 0, stream>>>(out_sgt, hg_t3, out_sgd, hg_d3,
      zb1t, zb2t, zb1d, zb2d, rs_t, dg_t, rs_d, dg_d);
  k_nce5<<<dim3(NSTRIP, 125 + 94), 256, 0, stream>>>(
      zb1t, zb2t, rs_t, zb1d, zb2d, rs_d);
  k_contrast<<<1, 256, 0, stream>>>(rs_t, dg_t, rs_d, dg_d, out_con);

  // ---- prediction head ----
  k_gather<<<(N_B + 3) / 4, 256, 0, stream>>>(out_sgt, hg_t3, out_sgd, hg_d3,
      tids, dids, gW, mlp_in_b, out_gmf, g_lin, N_B);
  k_mfma<256, 2, 1, 0, 1, 0><<<N_B / 32, 256, 0, stream>>>(
      mlp_in_b, W1b, b1, nullptr, h1buf, nullptr, nullptr, N_B);
  k_final<<<(N_B + 3) / 4, 256, 0, stream>>>(h1buf, W2, b2, g_lin, gb,
      out_gmf, out_fusion, out_mlp, N_B);
}

// Round 10
// 453.470 us; speedup vs baseline: 1.1164x; 1.1164x over previous
//
#include <hip/hip_runtime.h>
#include <math.h>

#define N_T 8000
#define N_D 6000
#define N_E 320000
#define N_B 16384
#define NSTRIP 9

typedef __attribute__((ext_vector_type(8))) short s16x8;
typedef __attribute__((ext_vector_type(8))) __bf16 bf16x8;
typedef __attribute__((ext_vector_type(4))) float f32x4;

static __device__ __forceinline__ f32x4 mfma16(s16x8 a, s16x8 b, f32x4 c) {
  return __builtin_amdgcn_mfma_f32_16x16x32_bf16(
      __builtin_bit_cast(bf16x8, a), __builtin_bit_cast(bf16x8, b), c, 0, 0, 0);
}

static __device__ __forceinline__ unsigned short f2bf(float f) {
  unsigned u = __float_as_uint(f);
  u += 0x7FFF + ((u >> 16) & 1);
  return (unsigned short)(u >> 16);
}

static __device__ __forceinline__ float bf2f(unsigned short u) {
  return __uint_as_float(((unsigned)u) << 16);
}

__device__ __forceinline__ float wave_sum(float v) {
  v += __shfl_xor(v, 32, 64);
  v += __shfl_xor(v, 16, 64);
  v += __shfl_xor(v, 8, 64);
  v += __shfl_xor(v, 4, 64);
  v += __shfl_xor(v, 2, 64);
  v += __shfl_xor(v, 1, 64);
  return v;
}

// ---------------- CSR build (merged T+D) ----------------
__global__ void k_hist2(const int* __restrict__ src, const int* __restrict__ tgt,
                        int* __restrict__ cnt) {
  int i = blockIdx.x * 256 + threadIdx.x;
  if (i < N_E) atomicAdd(&cnt[src[i]], 1);
  else if (i < 2 * N_E) atomicAdd(&cnt[N_T + tgt[i - N_E]], 1);
}

__global__ void k_scan2(const int* __restrict__ cnt, int* __restrict__ rp_t,
    int* __restrict__ cur_t, int* __restrict__ rp_d, int* __restrict__ cur_d) {
  const int* c = blockIdx.x ? cnt + N_T : cnt;
  const int n = blockIdx.x ? N_D : N_T;
  int* rp = blockIdx.x ? rp_d : rp_t;
  int* cur = blockIdx.x ? cur_d : cur_t;
  __shared__ int buf[1024];
  __shared__ int carry_s;
  if (threadIdx.x == 0) carry_s = 0;
  __syncthreads();
  for (int base = 0; base < n; base += 1024) {
    int c0 = carry_s;
    int i = base + (int)threadIdx.x;
    int v = (i < n) ? c[i] : 0;
    buf[threadIdx.x] = v;
    __syncthreads();
    for (int off = 1; off < 1024; off <<= 1) {
      int t = (threadIdx.x >= (unsigned)off) ? buf[threadIdx.x - off] : 0;
      __syncthreads();
      buf[threadIdx.x] += t;
      __syncthreads();
    }
    int incl = buf[threadIdx.x];
    if (i < n) { int e = c0 + incl - v; rp[i] = e; cur[i] = e; }
    __syncthreads();
    if (threadIdx.x == 0) carry_s = c0 + buf[1023];
    __syncthreads();
  }
  if (threadIdx.x == 0) rp[n] = carry_s;
}

__global__ void k_scatter2(const int* __restrict__ src, const int* __restrict__ tgt,
    int* __restrict__ cur_t, int* __restrict__ cur_d,
    int* __restrict__ nbr_t, int* __restrict__ nbr_d) {
  int i = blockIdx.x * 256 + threadIdx.x;
  if (i < N_E) {
    int p = atomicAdd(&cur_t[src[i]], 1);
    nbr_t[p] = tgt[i];
  } else if (i < 2 * N_E) {
    i -= N_E;
    int p = atomicAdd(&cur_d[tgt[i]], 1);
    nbr_d[p] = src[i];
  }
}

// ---------------- fat precompute: pgemm (0..7) | wvec6 (8..13) | tobf16 (14..891) ----------------
__global__ __launch_bounds__(256) void k_pre(const float* __restrict__ th,
    const float* __restrict__ dh, float* __restrict__ P_t, float* __restrict__ P_d,
    const float* __restrict__ WsT, const float* __restrict__ aT,
    const float* __restrict__ WsD, const float* __restrict__ aD, float* __restrict__ wv,
    const float* __restrict__ c0, unsigned short* __restrict__ y0,
    const float* __restrict__ c1, unsigned short* __restrict__ y1,
    const float* __restrict__ c2, unsigned short* __restrict__ y2,
    const float* __restrict__ c3, unsigned short* __restrict__ y3) {
  int bx = blockIdx.x;
  if (bx < 8) {
    const float* A = bx < 4 ? th : dh;
    float* C = bx < 4 ? P_t : P_d;
    const int sub = bx & 3;
    const int row0 = (sub >> 1) * 64, col0 = (sub & 1) * 64;
    __shared__ float As[16][65];
    __shared__ float Bs[16][65];
    const int tid = threadIdx.x;
    const int tr = tid >> 4, tc = tid & 15;
    float acc[4][4] = {};
    for (int k0 = 0; k0 < 256; k0 += 16) {
      {
        int m = tid >> 2, kk = (tid & 3) * 4;
        float4 v = *(const float4*)(A + (size_t)(row0 + m) * 256 + k0 + kk);
        As[kk + 0][m] = v.x; As[kk + 1][m] = v.y; As[kk + 2][m] = v.z; As[kk + 3][m] = v.w;
      }
      {
        int nn = tid >> 2, kk = (tid & 3) * 4;
        float4 v = *(const float4*)(A + (size_t)(col0 + nn) * 256 + k0 + kk);
        Bs[kk + 0][nn] = v.x; Bs[kk + 1][nn] = v.y; Bs[kk + 2][nn] = v.z; Bs[kk + 3][nn] = v.w;
      }
      __syncthreads();
#pragma unroll
      for (int k = 0; k < 16; ++k) {
        float a[4], b[4];
#pragma unroll
        for (int i = 0; i < 4; ++i) a[i] = As[k][tr * 4 + i];
#pragma unroll
        for (int j = 0; j < 4; ++j) b[j] = Bs[k][tc * 4 + j];
#pragma unroll
        for (int i = 0; i < 4; ++i)
#pragma unroll
          for (int j = 0; j < 4; ++j)
            acc[i][j] = fmaf(a[i], b[j], acc[i][j]);
      }
      __syncthreads();
    }
#pragma unroll
    for (int i = 0; i < 4; ++i)
#pragma unroll
      for (int j = 0; j < 4; ++j)
        C[(size_t)(row0 + tr * 4 + i) * 128 + col0 + tc * 4 + j] = acc[i][j];
  } else if (bx < 14) {
    if (threadIdx.x >= 128) return;
    int b = bx - 8, k = threadIdx.x;
    const float* W = b < 3 ? WsT + b * 16384 : WsD + (b - 3) * 16384;
    const float* a = b < 3 ? aT + b * 256 : aD + (b - 3) * 256;
    float s = 0.f;
    for (int n = 0; n < 128; ++n) s = fmaf(W[n * 128 + k], a[n], s);
    wv[b * 128 + k] = s;
  } else {
    int i = (bx - 14) * 256 + threadIdx.x;
    const float* x; unsigned short* y;
    if (i < 12288) { x = c0; y = y0; }
    else if (i < 24576) { x = c1; y = y1; i -= 12288; }
    else if (i < 32768) { x = c2; y = y2; i -= 24576; }
    else if (i < 224768) { x = c3; y = y3; i -= 32768; }
    else return;
    float4 v = ((const float4*)x)[i];
    ushort4 o;
    o.x = f2bf(v.x); o.y = f2bf(v.y); o.z = f2bf(v.z); o.w = f2bf(v.w);
    ((ushort4*)y)[i] = o;
  }
}

// ---------------- bf16 MFMA GEMM body, N=128 fixed, 32-row tile ----------------
template<int K, int ACT, int BIAS, int SJMODE, int OUTF, int OUTB>
static __device__ __forceinline__ void mfma_body(
    const unsigned short* __restrict__ A, const unsigned short* __restrict__ B,
    const float* __restrict__ bias, const float* __restrict__ a2,
    float* __restrict__ Cf, unsigned short* __restrict__ Cb,
    float* __restrict__ sj_out, int M, int bx) {
  const int wave = threadIdx.x >> 6, lane = threadIdx.x & 63;
  const int row0 = bx * 32;
  const int col0 = wave * 32;
  const int l15 = lane & 15, kg = lane >> 4;
  constexpr int NS = K / 32;
  f32x4 acc[2][2] = {};
  s16x8 ab[2][2], bb[2][2];
  auto ld = [&](int buf, int k0) {
#pragma unroll
    for (int i = 0; i < 2; ++i) {
      int r = row0 + i * 16 + l15;
      ab[buf][i] = (r < M) ? *(const s16x8*)(A + (size_t)r * K + k0 + kg * 8) : (s16x8)0;
    }
#pragma unroll
    for (int j = 0; j < 2; ++j) {
      int c = col0 + j * 16 + l15;
      bb[buf][j] = *(const s16x8*)(B + (size_t)c * K + k0 + kg * 8);
    }
  };
  ld(0, 0);
#pragma unroll
  for (int s = 0; s < NS; ++s) {
    if (s + 1 < NS) ld((s + 1) & 1, (s + 1) * 32);
#pragma unroll
    for (int i = 0; i < 2; ++i)
#pragma unroll
      for (int j = 0; j < 2; ++j)
        acc[i][j] = mfma16(ab[s & 1][i], bb[s & 1][j], acc[i][j]);
  }
  __shared__ float sjl[4][32];
  float a2v[2];
  if (SJMODE) {
#pragma unroll
    for (int j = 0; j < 2; ++j) a2v[j] = a2[col0 + j * 16 + l15];
  }
#pragma unroll
  for (int i = 0; i < 2; ++i) {
    float part[4] = {0.f, 0.f, 0.f, 0.f};
#pragma unroll
    for (int j = 0; j < 2; ++j) {
      int gc = col0 + j * 16 + l15;
      float bv = BIAS ? bias[gc] : 0.f;
#pragma unroll
      for (int r = 0; r < 4; ++r) {
        int gr = row0 + i * 16 + kg * 4 + r;
        float v = acc[i][j][r] + bv;
        if (SJMODE == 1) part[r] += v * a2v[j];
        if (ACT == 1) v = v > 0.f ? v : __expf(v) - 1.f;
        if (ACT == 2) v = fmaxf(v, 0.f);
        if (SJMODE == 2) part[r] += v * a2v[j];
        if (gr < M) {
          if (OUTF) Cf[(size_t)gr * 128 + gc] = v;
          if (OUTB) Cb[(size_t)gr * 128 + gc] = f2bf(v);
        }
      }
    }
    if (SJMODE) {
#pragma unroll
      for (int r = 0; r < 4; ++r) {
        float p = part[r];
        p += __shfl_xor(p, 1, 64);
        p += __shfl_xor(p, 2, 64);
        p += __shfl_xor(p, 4, 64);
        p += __shfl_xor(p, 8, 64);
        if (l15 == 0) sjl[wave][i * 16 + kg * 4 + r] = p;
      }
    }
  }
  if (SJMODE) {
    __syncthreads();
    if (threadIdx.x < 32) {
      int gr = row0 + (int)threadIdx.x;
      if (gr < M)
        sj_out[gr] = sjl[0][threadIdx.x] + sjl[1][threadIdx.x] +
                     sjl[2][threadIdx.x] + sjl[3][threadIdx.x];
    }
  }
}

template<int K, int ACT, int BIAS, int SJMODE, int OUTF, int OUTB>
__global__ __launch_bounds__(256) void k_mfma(const unsigned short* __restrict__ A,
    const unsigned short* __restrict__ B, const float* __restrict__ bias,
    const float* __restrict__ a2, float* __restrict__ Cf, unsigned short* __restrict__ Cb,
    float* __restrict__ sj_out, int M) {
  mfma_body<K, ACT, BIAS, SJMODE, OUTF, OUTB>(A, B, bias, a2, Cf, Cb, sj_out, M, blockIdx.x);
}

template<int K, int ACT, int SJMODE, int OUTF, int OUTB>
__global__ __launch_bounds__(256) void k_mfma2(
    const unsigned short* __restrict__ A0, const unsigned short* __restrict__ B0,
    const float* __restrict__ a20, float* __restrict__ Cf0,
    unsigned short* __restrict__ Cb0, float* __restrict__ sj0, int M0, int G0,
    const unsigned short* __restrict__ A1, const unsigned short* __restrict__ B1,
    const float* __restrict__ a21, float* __restrict__ Cf1,
    unsigned short* __restrict__ Cb1, float* __restrict__ sj1, int M1) {
  int bx = blockIdx.x;
  if (bx < G0)
    mfma_body<K, ACT, 0, SJMODE, OUTF, OUTB>(A0, B0, nullptr, a20, Cf0, Cb0, sj0, M0, bx);
  else
    mfma_body<K, ACT, 0, SJMODE, OUTF, OUTB>(A1, B1, nullptr, a21, Cf1, Cb1, sj1, M1, bx - G0);
}

// ---------------- NCE: direct-global B, A resident (64x64/wave), staggered ----------------
// z1 pre-scaled by 2 (1/TEMP folded at normalize); z2 alloc padded so unguarded
// loads stay in-bounds; epilogue col-guard masks pad columns.
__global__ __launch_bounds__(256) void k_nce4(
    const unsigned short* __restrict__ z1t, const unsigned short* __restrict__ z2t,
    float* __restrict__ rs_tp,
    const unsigned short* __restrict__ z1d, const unsigned short* __restrict__ z2d,
    float* __restrict__ rs_dp) {
  const int wave = threadIdx.x >> 6, lane = threadIdx.x & 63;
  const int l15 = lane & 15, kg = lane >> 4;
  int by = blockIdx.y;
  const unsigned short *z1, *z2; float* rowsum; int M, N;
  if (by < 63) { z1 = z1t; z2 = z2t; rowsum = rs_tp; M = N_T; N = N_T; }
  else { by -= 63; z1 = z1d; z2 = z2d; rowsum = rs_dp; M = N_D; N = N_D; }
  const int row0 = by * 128 + (wave >> 1) * 64;
  const int colw = (wave & 1) * 64;
  const int CT = (N + 127) >> 7;
  const int ctps = (CT + NSTRIP - 1) / NSTRIP;
  const int ct0 = blockIdx.x * ctps;
  const int ct1 = min(CT, ct0 + ctps);
  const int nct = ct1 - ct0;
  if (nct <= 0) return;
  s16x8 a[4][4];
#pragma unroll
  for (int ks = 0; ks < 4; ++ks)
#pragma unroll
    for (int i = 0; i < 4; ++i) {
      int r = row0 + i * 16 + l15;
      a[ks][i] = (r < M) ? *(const s16x8*)(z1 + (size_t)r * 128 + ks * 32 + kg * 8) : (s16x8)0;
    }
  s16x8 b[2][4];
  auto ldb = [&](int buf, int ct, int ks) {
    const unsigned short* base = z2 + (size_t)(ct * 128 + colw) * 128 + ks * 32 + kg * 8;
#pragma unroll
    for (int j = 0; j < 4; ++j)
      b[buf][j] = *(const s16x8*)(base + (size_t)(j * 16 + l15) * 128);
  };
  float rs[4][4] = {};
  int cs = by % nct;          // stagger start tile per row-block (de-convoy L2)
  ldb(0, ct0 + cs, 0);
  for (int cc = 0; cc < nct; ++cc) {
    const int ct = ct0 + cs;
    const int csn = (cs + 1 == nct) ? 0 : cs + 1;
    f32x4 acc[4][4] = {};
#pragma unroll
    for (int ks = 0; ks < 4; ++ks) {
      if (ks < 3) ldb((ks + 1) & 1, ct, ks + 1);
      else if (cc + 1 < nct) ldb(0, ct0 + csn, 0);  // prefetch next tile under epilogue
#pragma unroll
      for (int i = 0; i < 4; ++i)
#pragma unroll
        for (int j = 0; j < 4; ++j)
          acc[i][j] = mfma16(a[ks][i], b[ks & 1][j], acc[i][j]);
    }
    const int c0 = ct * 128 + colw;
#pragma unroll
    for (int j = 0; j < 4; ++j) {
      bool cok = c0 + j * 16 + l15 < N;
      if (cok) {
#pragma unroll
        for (int i = 0; i < 4; ++i)
#pragma unroll
          for (int r = 0; r < 4; ++r)
            rs[i][r] += __expf(acc[i][j][r]);   // acc = 2*sim (z1 pre-scaled)
      }
    }
    cs = csn;
  }
#pragma unroll
  for (int i = 0; i < 4; ++i)
#pragma unroll
    for (int r = 0; r < 4; ++r) {
      float v = rs[i][r];
      v += __shfl_xor(v, 1, 64);
      v += __shfl_xor(v, 2, 64);
      v += __shfl_xor(v, 4, 64);
      v += __shfl_xor(v, 8, 64);
      if (l15 == 0) {
        int gr = row0 + i * 16 + kg * 4 + r;
        if (gr < M) atomicAdd(&rowsum[gr], v);
      }
    }
}

// ---------------- G partials: both sides, 128-way split-K each ----------------
__global__ __launch_bounds__(256) void k_syrk2m(const unsigned short* __restrict__ xbT,
    const unsigned short* __restrict__ xbD, float* __restrict__ partT,
    float* __restrict__ partD) {
  int b = blockIdx.x;
  const unsigned short* xb; float* part; int n;
  if (b < 128) { xb = xbT; part = partT + (size_t)b * 16384; n = N_T; }
  else { b -= 128; xb = xbD; part = partD + (size_t)b * 16384; n = N_D; }
  __shared__ float rows[4][128];
  int chunk = (n + 127) >> 7;
  int m0 = b * chunk, m1 = min(n, m0 + chunk);
  int tx = threadIdx.x & 15, ty = threadIdx.x >> 4;
  float acc[8][8] = {};
  for (int m = m0; m < m1; m += 4) {
    int nr = min(4, m1 - m);
    if ((int)threadIdx.x < nr * 64) {
      ushort2 u = ((const ushort2*)(xb + (size_t)m * 128))[threadIdx.x];
      rows[threadIdx.x >> 6][(threadIdx.x & 63) * 2] = bf2f(u.x);
      rows[threadIdx.x >> 6][(threadIdx.x & 63) * 2 + 1] = bf2f(u.y);
    }
    __syncthreads();
    for (int r = 0; r < nr; ++r) {
      float a[8], bv[8];
#pragma unroll
      for (int i = 0; i < 8; ++i) a[i] = rows[r][i * 16 + ty];
#pragma unroll
      for (int j = 0; j < 8; ++j) bv[j] = rows[r][j * 16 + tx];
#pragma unroll
      for (int i = 0; i < 8; ++i)
#pragma unroll
        for (int j = 0; j < 8; ++j)
          acc[i][j] = fmaf(a[i], bv[j], acc[i][j]);
    }
    __syncthreads();
  }
#pragma unroll
  for (int i = 0; i < 8; ++i)
#pragma unroll
    for (int j = 0; j < 8; ++j)
      part[(i * 16 + ty) * 128 + j * 16 + tx] = acc[i][j];
}

__global__ void k_redm(const float* __restrict__ partT, const float* __restrict__ partD,
                       float* __restrict__ GmT, float* __restrict__ GmD) {
  int b = blockIdx.x;
  const float* part = b < 64 ? partT : partD;
  float* G = b < 64 ? GmT : GmD;
  int i = (b & 63) * 256 + threadIdx.x;
  float s = 0.f;
  for (int c = 0; c < 128; ++c) s += part[(size_t)c * 16384 + i];
  G[i] = s;
}

// ---------------- Wt = G @ P -> bf16, both sides (8 blocks) ----------------
__global__ __launch_bounds__(256) void k_wtm(const float* __restrict__ GmT,
    const float* __restrict__ P_t, unsigned short* __restrict__ wb_t,
    const float* __restrict__ GmD, const float* __restrict__ P_d,
    unsigned short* __restrict__ wb_d) {
  const float* G = blockIdx.x < 4 ? GmT : GmD;
  const float* P = blockIdx.x < 4 ? P_t : P_d;
  unsigned short* wb = blockIdx.x < 4 ? wb_t : wb_d;
  const int sub = blockIdx.x & 3;
  const int bi = sub >> 1, bj = sub & 1;
  __shared__ float Gs[64][129];
  __shared__ float Ps[128][65];
  for (int t = threadIdx.x; t < 8192; t += 256) {
    int il = t >> 7, k = t & 127;
    Gs[il][k] = G[(bi * 64 + il) * 128 + k];
    int pk = t >> 6, pj = t & 63;
    Ps[pk][pj] = P[pk * 128 + bj * 64 + pj];
  }
  __syncthreads();
  const int tx = threadIdx.x & 15, ty = threadIdx.x >> 4;
  float acc[4][4] = {};
  for (int k = 0; k < 128; ++k) {
    float a[4], b[4];
#pragma unroll
    for (int i = 0; i < 4; ++i) a[i] = Gs[ty * 4 + i][k];
#pragma unroll
    for (int j = 0; j < 4; ++j) b[j] = Ps[k][tx * 4 + j];
#pragma unroll
    for (int i = 0; i < 4; ++i)
#pragma unroll
      for (int j = 0; j < 4; ++j)
        acc[i][j] = fmaf(a[i], b[j], acc[i][j]);
  }
#pragma unroll
  for (int i = 0; i < 4; ++i)
#pragma unroll
    for (int j = 0; j < 4; ++j)
      wb[(bi * 64 + ty * 4 + i) * 128 + bj * 64 + tx * 4 + j] = f2bf(acc[i][j]);
}

__global__ void k_rowdot2(const float* __restrict__ trna, const float* __restrict__ dis,
    const float* __restrict__ wv, float* __restrict__ si_ta, float* __restrict__ si_da) {
  int r = blockIdx.x * 4 + (threadIdx.x >> 6);
  int lane = threadIdx.x & 63;
  const float* h; const float* a; float* o; int row;
  if (r < N_T) { h = trna; a = wv; o = si_ta; row = r; }
  else {
    row = r - N_T;
    if (row >= N_D) return;
    h = dis; a = wv + 3 * 128; o = si_da;
  }
  float2 v = *(const float2*)(h + (size_t)row * 128 + lane * 2);
  float2 av = *(const float2*)(a + lane * 2);
  float s = v.x * av.x + v.y * av.y;
  s = wave_sum(s);
  if (lane == 0) o[row] = s;
}

// ---------------- aggregation: 1 row/wave, 2 cols/lane, 16-edge ILP ----------------
template<int OUTF, int OUTB, int EMIT_SI>
static __device__ __forceinline__ void agg_body(const int* __restrict__ rp,
    const int* __restrict__ nbr, const float* __restrict__ si,
    const float* __restrict__ sj, const unsigned short* __restrict__ hjb,
    float* __restrict__ outF, unsigned short* __restrict__ outB,
    const float* __restrict__ wv, float* __restrict__ si_out, int n, int bx) {
  int r = bx * 4 + ((int)threadIdx.x >> 6);
  int lane = threadIdx.x & 63;
  if (r >= n) return;
  int p0 = rp[r], p1 = rp[r + 1];
  float sir = si[r];
  int c2 = lane * 2;
  auto wgt = [&](float sv) {
    float v = sir + sv;
    v = v >= 0.f ? v : 0.2f * v;
    v = fminf(30.f, fmaxf(-30.f, v));
    return __expf(v);
  };
  float ax = 0.f, ay = 0.f, den = 0.f;
  int p = p0;
  for (; p + 16 <= p1; p += 16) {
    int t[16]; float sv[16]; ushort2 h[16];
#pragma unroll
    for (int k = 0; k < 16; ++k) t[k] = nbr[p + k];
#pragma unroll
    for (int k = 0; k < 16; ++k) sv[k] = sj[t[k]];
#pragma unroll
    for (int k = 0; k < 16; ++k) h[k] = *(const ushort2*)(hjb + (size_t)t[k] * 128 + c2);
#pragma unroll
    for (int k = 0; k < 16; ++k) {
      float w = wgt(sv[k]);
      den += w;
      ax += w * bf2f(h[k].x);
      ay += w * bf2f(h[k].y);
    }
  }
  for (; p + 4 <= p1; p += 4) {
    int t[4]; float sv[4]; ushort2 h[4];
#pragma unroll
    for (int k = 0; k < 4; ++k) t[k] = nbr[p + k];
#pragma unroll
    for (int k = 0; k < 4; ++k) sv[k] = sj[t[k]];
#pragma unroll
    for (int k = 0; k < 4; ++k) h[k] = *(const ushort2*)(hjb + (size_t)t[k] * 128 + c2);
#pragma unroll
    for (int k = 0; k < 4; ++k) {
      float w = wgt(sv[k]);
      den += w;
      ax += w * bf2f(h[k].x);
      ay += w * bf2f(h[k].y);
    }
  }
  for (; p < p1; ++p) {
    int t = nbr[p];
    float w = wgt(sj[t]);
    ushort2 h = *(const ushort2*)(hjb + (size_t)t * 128 + c2);
    den += w;
    ax += w * bf2f(h.x);
    ay += w * bf2f(h.y);
  }
  float inv = 1.0f / (den + 1e-8f);
  float vx = ax * inv, vy = ay * inv;
  vx = vx > 0.f ? vx : __expf(vx) - 1.f;
  vy = vy > 0.f ? vy : __expf(vy) - 1.f;
  if (OUTF) {
    float2 of; of.x = vx; of.y = vy;
    *(float2*)(outF + (size_t)r * 128 + c2) = of;
  }
  if (OUTB) {
    ushort2 ob; ob.x = f2bf(vx); ob.y = f2bf(vy);
    *(ushort2*)(outB + (size_t)r * 128 + c2) = ob;
  }
  if (EMIT_SI) {
    float2 w2v = *(const float2*)(wv + c2);
    float d = vx * w2v.x + vy * w2v.y;
    d = wave_sum(d);
    if (lane == 0) si_out[r] = d;
  }
}

template<int OUTF, int OUTB, int EMIT_SI>
__global__ __launch_bounds__(256) void k_agg(const int* __restrict__ rp,
    const int* __restrict__ nbr, const float* __restrict__ si,
    const float* __restrict__ sj, const unsigned short* __restrict__ hjb,
    float* __restrict__ outF, unsigned short* __restrict__ outB,
    const float* __restrict__ wv, float* __restrict__ si_out, int n) {
  agg_body<OUTF, OUTB, EMIT_SI>(rp, nbr, si, sj, hjb, outF, outB, wv, si_out, n, blockIdx.x);
}

template<int OUTF, int OUTB, int EMIT_SI>
__global__ __launch_bounds__(256) void k_agg2(
    const int* __restrict__ rp0, const int* __restrict__ nbr0, const float* __restrict__ si0,
    const float* __restrict__ sj0, const unsigned short* __restrict__ hjb0,
    float* __restrict__ outF0, unsigned short* __restrict__ outB0,
    const float* __restrict__ wv0, float* __restrict__ sio0, int n0, int G0,
    const int* __restrict__ rp1, const int* __restrict__ nbr1, const float* __restrict__ si1,
    const float* __restrict__ sj1, const unsigned short* __restrict__ hjb1,
    float* __restrict__ outF1, unsigned short* __restrict__ outB1,
    const float* __restrict__ wv1, float* __restrict__ sio1, int n1) {
  int bx = blockIdx.x;
  if (bx < G0)
    agg_body<OUTF, OUTB, EMIT_SI>(rp0, nbr0, si0, sj0, hjb0, outF0, outB0, wv0, sio0, n0, bx);
  else
    agg_body<OUTF, OUTB, EMIT_SI>(rp1, nbr1, si1, sj1, hjb1, outF1, outB1, wv1, sio1, n1, bx - G0);
}

// ---------------- normalize both z's per row + diag dot + rs zero ----------------
// z1 outputs pre-scaled by 2 (1/TEMP) for the NCE kernel.
__global__ void k_norm2(const float* __restrict__ sgt, const float* __restrict__ hgt3,
    const float* __restrict__ sgd, const float* __restrict__ hgd3,
    unsigned short* __restrict__ z1t, unsigned short* __restrict__ z2t,
    unsigned short* __restrict__ z1d, unsigned short* __restrict__ z2d,
    float* __restrict__ rs_t, float* __restrict__ dg_t,
    float* __restrict__ rs_d, float* __restrict__ dg_d) {
  int ridx = blockIdx.x * 4 + (threadIdx.x >> 6);
  int lane = threadIdx.x & 63;
  const float *x1, *x2; unsigned short *o1, *o2; float *rs, *dg; int row;
  if (ridx < 8000) { x1 = sgt; x2 = hgt3; o1 = z1t; o2 = z2t; rs = rs_t; dg = dg_t; row = ridx; }
  else if (ridx < 14000) {
    row = ridx - 8000;
    x1 = sgd; x2 = hgd3; o1 = z1d; o2 = z2d; rs = rs_d; dg = dg_d;
  } else return;
  float2 v1 = *(const float2*)(x1 + (size_t)row * 128 + lane * 2);
  float2 v2 = *(const float2*)(x2 + (size_t)row * 128 + lane * 2);
  float ss1 = wave_sum(v1.x * v1.x + v1.y * v1.y);
  float ss2 = wave_sum(v2.x * v2.x + v2.y * v2.y);
  float i1 = 1.0f / (sqrtf(ss1) + 1e-12f);
  float i2 = 1.0f / (sqrtf(ss2) + 1e-12f);
  float n1x = v1.x * i1, n1y = v1.y * i1;
  float n2x = v2.x * i2, n2y = v2.y * i2;
  ushort2 w1; w1.x = f2bf(n1x + n1x); w1.y = f2bf(n1y + n1y);   // x2 fold
  ushort2 w2; w2.x = f2bf(n2x); w2.y = f2bf(n2y);
  *(ushort2*)(o1 + (size_t)row * 128 + lane * 2) = w1;
  *(ushort2*)(o2 + (size_t)row * 128 + lane * 2) = w2;
  float d = wave_sum(n1x * n2x + n1y * n2y);
  if (lane == 0) { dg[row] = 2.0f * d; rs[row] = 0.f; }
}

__global__ void k_gather(const float* __restrict__ sgt, const float* __restrict__ hgt,
    const float* __restrict__ sgd, const float* __restrict__ hgd,
    const int* __restrict__ tids, const int* __restrict__ dids,
    const float* __restrict__ gateW, unsigned short* __restrict__ mlp_in_b,
    float* __restrict__ gmf, float* __restrict__ gate_lin, int nB) {
  int b = blockIdx.x * 4 + (threadIdx.x >> 6);
  int lane = threadIdx.x & 63;
  if (b >= nB) return;
  int ti = tids[b], di = dids[b];
  float2 a1 = *(const float2*)(sgt + (size_t)ti * 128 + lane * 2);
  float2 a2 = *(const float2*)(hgt + (size_t)ti * 128 + lane * 2);
  float2 c1 = *(const float2*)(sgd + (size_t)di * 128 + lane * 2);
  float2 c2 = *(const float2*)(hgd + (size_t)di * 128 + lane * 2);
  float2 st; st.x = a1.x + a2.x; st.y = a1.y + a2.y;
  float2 sd; sd.x = c1.x + c2.x; sd.y = c1.y + c2.y;
  ushort2 o1; o1.x = f2bf(st.x); o1.y = f2bf(st.y);
  ushort2 o2; o2.x = f2bf(sd.x); o2.y = f2bf(sd.y);
  *(ushort2*)(mlp_in_b + (size_t)b * 256 + lane * 2) = o1;
  *(ushort2*)(mlp_in_b + (size_t)b * 256 + 128 + lane * 2) = o2;
  float2 gv; gv.x = st.x * sd.x; gv.y = st.y * sd.y;
  float2 gw = *(const float2*)(gateW + lane * 2);
  float s1 = gv.x + gv.y;
  float s2 = gv.x * gw.x + gv.y * gw.y;
  s1 = wave_sum(s1);
  s2 = wave_sum(s2);
  if (lane == 0) { gmf[b] = s1; gate_lin[b] = s2; }
}

__global__ void k_final(const float* __restrict__ h1, const float* __restrict__ W2,
    const float* __restrict__ b2, const float* __restrict__ gate_lin,
    const float* __restrict__ gate_b, const float* __restrict__ gmf,
    float* __restrict__ fusion, float* __restrict__ mlp_pred, int nB) {
  int b = blockIdx.x * 4 + (threadIdx.x >> 6);
  int lane = threadIdx.x & 63;
  if (b >= nB) return;
  float2 hv = *(const float2*)(h1 + (size_t)b * 128 + lane * 2);
  float2 wv = *(const float2*)(W2 + lane * 2);
  float s = hv.x * wv.x + hv.y * wv.y;
  s = wave_sum(s);
  if (lane == 0) {
    float mp = s + b2[0];
    float g = 1.0f / (1.0f + __expf(-(gate_lin[b] + gate_b[0])));
    mlp_pred[b] = mp;
    fusion[b] = g * gmf[b] + (1.0f - g) * mp;
  }
}

__global__ void k_contrast(const float* __restrict__ rs_t, const float* __restrict__ dg_t,
    const float* __restrict__ rs_d, const float* __restrict__ dg_d, float* __restrict__ out) {
  __shared__ float red[1024];
  float st = 0.f, sd = 0.f;
  for (int i = threadIdx.x; i < N_T; i += 1024) st += __logf(rs_t[i]) - dg_t[i];
  for (int i = threadIdx.x; i < N_D; i += 1024) sd += __logf(rs_d[i]) - dg_d[i];
  red[threadIdx.x] = st * (1.0f / N_T) + sd * (1.0f / N_D);
  __syncthreads();
  for (int off = 512; off; off >>= 1) {
    if (threadIdx.x < (unsigned)off) red[threadIdx.x] += red[threadIdx.x + off];
    __syncthreads();
  }
  if (threadIdx.x == 0) out[0] = red[0];
}

// ---------------- host orchestration ----------------
extern "C" void kernel_launch(void* const* d_in, const int* in_sizes, int n_in,
                              void* d_out, int out_size, void* d_ws, size_t ws_size,
                              hipStream_t stream) {
  const float* trna   = (const float*)d_in[0];
  const float* dis    = (const float*)d_in[1];
  const float* thyper = (const float*)d_in[2];
  const float* dhyper = (const float*)d_in[3];
  const float* WsrcT  = (const float*)d_in[4];
  const float* WtgtT  = (const float*)d_in[5];
  const float* aT     = (const float*)d_in[6];
  const float* WsrcD  = (const float*)d_in[7];
  const float* WtgtD  = (const float*)d_in[8];
  const float* aD     = (const float*)d_in[9];
  const float* W1     = (const float*)d_in[10];
  const float* b1     = (const float*)d_in[11];
  const float* W2     = (const float*)d_in[12];
  const float* b2     = (const float*)d_in[13];
  const float* gW     = (const float*)d_in[14];
  const float* gb     = (const float*)d_in[15];
  const int* src_id   = (const int*)d_in[16];
  const int* tgt_id   = (const int*)d_in[17];
  const int* tids     = (const int*)d_in[18];
  const int* dids     = (const int*)d_in[19];
  float* out = (float*)d_out;

  float* out_fusion = out;
  float* out_sgt    = out + 16384;
  float* out_sgd    = out + 16384 + 1024000;
  float* out_gmf    = out + 1808384;
  float* out_mlp    = out + 1824768;
  float* out_con    = out + 1841152;

  char* wsb = (char*)d_ws;
  size_t off = 0;
  auto alloc = [&](size_t bytes) -> void* {
    void* p = wsb + off;
    off += (bytes + 255) & ~(size_t)255;
    return p;
  };
  float* hg_t3  = (float*)alloc((size_t)N_T * 128 * 4);
  float* hg_d3  = (float*)alloc((size_t)N_D * 128 * 4);
  unsigned short* sgt_b  = (unsigned short*)alloc((size_t)N_T * 128 * 2);
  unsigned short* sgd_b  = (unsigned short*)alloc((size_t)N_D * 128 * 2);
  unsigned short* hgt_b  = (unsigned short*)alloc((size_t)N_T * 128 * 2);
  unsigned short* hgd_b  = (unsigned short*)alloc((size_t)N_D * 128 * 2);
  unsigned short* hgt2_b = (unsigned short*)alloc((size_t)N_T * 128 * 2);
  unsigned short* hgd2_b = (unsigned short*)alloc((size_t)N_D * 128 * 2);
  unsigned short* disb   = (unsigned short*)alloc((size_t)N_D * 128 * 2);
  unsigned short* hjbT   = (unsigned short*)alloc((size_t)N_T * 128 * 2);
  unsigned short* hjbD   = (unsigned short*)alloc((size_t)N_T * 128 * 2);
  unsigned short* zb1t = (unsigned short*)alloc((size_t)N_T * 128 * 2);
  unsigned short* zb2t = (unsigned short*)alloc((size_t)(N_T + 128) * 128 * 2);  // padded
  unsigned short* zb1d = (unsigned short*)alloc((size_t)N_D * 128 * 2);
  unsigned short* zb2d = (unsigned short*)alloc((size_t)(N_D + 128) * 128 * 2);  // padded
  unsigned short* wb_t = (unsigned short*)alloc(16384 * 2);
  unsigned short* wb_d = (unsigned short*)alloc(16384 * 2);
  unsigned short* wbT  = (unsigned short*)alloc(3 * 16384 * 2);
  unsigned short* wbD  = (unsigned short*)alloc(3 * 16384 * 2);
  unsigned short* W1b  = (unsigned short*)alloc(32768 * 2);
  unsigned short* mlp_in_b = (unsigned short*)alloc((size_t)N_B * 256 * 2);  // 8 MB
  float* h1buf  = (float*)alloc((size_t)N_B * 128 * 4);                      // 8 MB
  float* partT  = (float*)mlp_in_b;   // aliased, disjoint in time
  float* partD  = partT + (size_t)128 * 16384;
  float* Gm_t   = (float*)alloc(16384 * 4);
  float* Gm_d   = (float*)alloc(16384 * 4);
  float* P_t    = (float*)alloc(16384 * 4);
  float* P_d    = (float*)alloc(16384 * 4);
  float* wvecs  = (float*)alloc(6 * 128 * 4);
  float* si_ta  = (float*)alloc(N_T * 4);
  float* si_tb  = (float*)alloc(N_T * 4);
  float* si_da  = (float*)alloc(N_D * 4);
  float* si_db  = (float*)alloc(N_D * 4);
  float* s_jT   = (float*)alloc(N_T * 4);
  float* s_jD   = (float*)alloc(N_T * 4);
  int* cnt      = (int*)alloc((N_T + N_D) * 4);
  int* rp_t     = (int*)alloc((N_T + 1) * 4);
  int* cur_t    = (int*)alloc(N_T * 4);
  int* rp_d     = (int*)alloc((N_D + 1) * 4);
  int* cur_d    = (int*)alloc(N_D * 4);
  int* nbrc_t   = (int*)alloc((size_t)N_E * 4);
  int* nbrc_d   = (int*)alloc((size_t)N_E * 4);
  float* rs_t   = (float*)alloc(N_T * 4);
  float* dg_t   = (float*)alloc(N_T * 4);
  float* rs_d   = (float*)alloc(N_D * 4);
  float* dg_d   = (float*)alloc(N_D * 4);
  float* g_lin  = (float*)alloc(N_B * 4);
  (void)ws_size; (void)in_sizes; (void)n_in; (void)out_size;

  const int gT32 = (N_T + 31) / 32;   // 250
  const int gD32 = (N_D + 31) / 32;   // 188
  const int aT4 = (N_T + 3) / 4, aD4 = (N_D + 3) / 4;

  // ---- CSR ----
  hipMemsetAsync(cnt, 0, (N_T + N_D) * 4, stream);
  k_hist2<<<(2 * N_E + 255) / 256, 256, 0, stream>>>(src_id, tgt_id, cnt);
  k_scan2<<<2, 1024, 0, stream>>>(cnt, rp_t, cur_t, rp_d, cur_d);
  k_scatter2<<<(2 * N_E + 255) / 256, 256, 0, stream>>>(src_id, tgt_id, cur_t, cur_d,
      nbrc_t, nbrc_d);

  // ---- precomputes (fat kernel) + rowdot ----
  k_pre<<<892, 256, 0, stream>>>(thyper, dhyper, P_t, P_d,
      WsrcT, aT, WsrcD, aD, wvecs,
      WtgtT, wbT, WtgtD, wbD, W1, W1b, dis, disb);
  k_rowdot2<<<(N_T + N_D + 3) / 4, 256, 0, stream>>>(trna, dis, wvecs, si_ta, si_da);

  // ---- GAT layer 1 (serial T -> D) ----
  k_mfma<128, 0, 0, 1, 0, 1><<<gD32, 256, 0, stream>>>(
      disb, wbT, nullptr, aT + 128, nullptr, hjbT, s_jT, N_D);
  k_agg<0, 1, 0><<<aT4, 256, 0, stream>>>(rp_t, nbrc_t, si_ta, s_jT, hjbT,
      nullptr, sgt_b, nullptr, nullptr, N_T);
  k_mfma<128, 0, 0, 1, 0, 1><<<gT32, 256, 0, stream>>>(
      sgt_b, wbD, nullptr, aD + 128, nullptr, hjbD, s_jD, N_T);
  k_agg<0, 1, 0><<<aD4, 256, 0, stream>>>(rp_d, nbrc_d, si_da, s_jD, hjbD,
      nullptr, sgd_b, nullptr, nullptr, N_D);

  // ---- hypergraph pass 1 (merged T+D) ----
  k_syrk2m<<<256, 256, 0, stream>>>(sgt_b, sgd_b, partT, partD);
  k_redm<<<128, 256, 0, stream>>>(partT, partD, Gm_t, Gm_d);
  k_wtm<<<8, 256, 0, stream>>>(Gm_t, P_t, wb_t, Gm_d, P_d, wb_d);
  k_mfma2<128, 1, 0, 0, 1><<<gT32 + gD32, 256, 0, stream>>>(
      sgt_b, wb_t, nullptr, nullptr, hgt_b, nullptr, N_T, gT32,
      sgd_b, wb_d, nullptr, nullptr, hgd_b, nullptr, N_D);

  // ---- hypergraph pass 2 (merged; emits si for GAT2) ----
  k_syrk2m<<<256, 256, 0, stream>>>(hgt_b, hgd_b, partT, partD);
  k_redm<<<128, 256, 0, stream>>>(partT, partD, Gm_t, Gm_d);
  k_wtm<<<8, 256, 0, stream>>>(Gm_t, P_t, wb_t, Gm_d, P_d, wb_d);
  k_mfma2<128, 1, 2, 0, 1><<<gT32 + gD32, 256, 0, stream>>>(
      hgt_b, wb_t, wvecs + 128, nullptr, hgt2_b, si_tb, N_T, gT32,
      hgd_b, wb_d, wvecs + 4 * 128, nullptr, hgd2_b, si_db, N_D);

  // ---- GAT layer 2 (merged T+D) ----
  k_mfma2<128, 0, 1, 0, 1><<<gD32 + gT32, 256, 0, stream>>>(
      hgd2_b, wbT + 16384, aT + 256 + 128, nullptr, hjbT, s_jT, N_D, gD32,
      hgt2_b, wbD + 16384, aD + 256 + 128, nullptr, hjbD, s_jD, N_T);
  k_agg2<0, 1, 1><<<aT4 + aD4, 256, 0, stream>>>(
      rp_t, nbrc_t, si_tb, s_jT, hjbT, nullptr, sgt_b, wvecs + 2 * 128, si_ta, N_T, aT4,
      rp_d, nbrc_d, si_db, s_jD, hjbD, nullptr, sgd_b, wvecs + 5 * 128, si_da, N_D);

  // ---- GAT layer 3 (serial T -> D) ----
  k_mfma<128, 0, 0, 1, 0, 1><<<gD32, 256, 0, stream>>>(
      sgd_b, wbT + 32768, nullptr, aT + 512 + 128, nullptr, hjbT, s_jT, N_D);
  k_agg<1, 1, 0><<<aT4, 256, 0, stream>>>(rp_t, nbrc_t, si_ta, s_jT, hjbT,
      out_sgt, sgt_b, nullptr, nullptr, N_T);
  k_mfma<128, 0, 0, 1, 0, 1><<<gT32, 256, 0, stream>>>(
      sgt_b, wbD + 32768, nullptr, aD + 512 + 128, nullptr, hjbD, s_jD, N_T);
  k_agg<1, 0, 0><<<aD4, 256, 0, stream>>>(rp_d, nbrc_d, si_da, s_jD, hjbD,
      out_sgd, nullptr, nullptr, nullptr, N_D);

  // ---- hypergraph pass 3 (merged) ----
  k_syrk2m<<<256, 256, 0, stream>>>(hgt2_b, hgd2_b, partT, partD);
  k_redm<<<128, 256, 0, stream>>>(partT, partD, Gm_t, Gm_d);
  k_wtm<<<8, 256, 0, stream>>>(Gm_t, P_t, wb_t, Gm_d, P_d, wb_d);
  k_mfma2<128, 1, 0, 1, 0><<<gT32 + gD32, 256, 0, stream>>>(
      hgt2_b, wb_t, nullptr, hg_t3, nullptr, nullptr, N_T, gT32,
      hgd2_b, wb_d, nullptr, hg_d3, nullptr, nullptr, N_D);

  // ---- InfoNCE ----
  k_norm2<<<3500, 256, 0, stream>>>(out_sgt, hg_t3, out_sgd, hg_d3,
      zb1t, zb2t, zb1d, zb2d, rs_t, dg_t, rs_d, dg_d);
  k_nce4<<<dim3(NSTRIP, 63 + 47), 256, 0, stream>>>(
      zb1t, zb2t, rs_t, zb1d, zb2d, rs_d);
  k_contrast<<<1, 1024, 0, stream>>>(rs_t, dg_t, rs_d, dg_d, out_con);

  // ---- prediction head ----
  k_gather<<<(N_B + 3) / 4, 256, 0, stream>>>(out_sgt, hg_t3, out_sgd, hg_d3,
      tids, dids, gW, mlp_in_b, out_gmf, g_lin, N_B);
  k_mfma<256, 2, 1, 0, 1, 0><<<N_B / 32, 256, 0, stream>>>(
      mlp_in_b, W1b, b1, nullptr, h1buf, nullptr, nullptr, N_B);
  k_final<<<(N_B + 3) / 4, 256, 0, stream>>>(h1buf, W2, b2, g_lin, gb,
      out_gmf, out_fusion, out_mlp, N_B);
}